// Round 22
// baseline (68.283 us; speedup 1.0000x reference)
//
#include <hip/hip_runtime.h>
#include <stdint.h>

// DetectionLoss for B=16, N=884736. Output: [cls_pos_loss, cls_neg_loss].
//
// R21: VGPR 20->32 but mono flat at 45us -> not register-starved; ~33% issue
// stall with ample TLP. R22: COALESCED loads — thread owns 4 group-strided
// quads (lane-consecutive float4s: each dwordx4 = 16 cache lines, was 64).
// Pure index remap; threefry counters/classify/selection identical.

#define BATCH 16
#define NPTS 884736u
#define THRESH_KEY 8266976u    // candidate keys >= this (tail 0.01450)
#define THRESH_W   4232691712u // THRESH_KEY<<9 (raw-word compare)
#define KEYMAX 8388607u
#define KSEL 10000u
// cut0 = 2^23 - KSEL*121632/12822 ~= 8293746 ; margin 8000 ~= 8.5 sigma
#define TLO 8285746u
#define THI 8301746u
#define TLO_W 4242301952u      // TLO<<9
#define HI_W  4250494464u      // (THI+1)<<9 : kw>=HI_W <=> key>THI
#define WCAP 3072u             // selection window LDS cap/sample (E~1687, sd 41)
#define WBCAP 40u              // per-block window region (E~7.8, +11 sigma)
#define SCAP 192               // per-block flagged staging (E~122, +6 sigma)
#define BCAP 64
#define NBLK2 216u             // mono grid.x ; 216*4096 = NPTS
#define HDRB 512               // per-sample header stride (hdr = 8192 B)

// ws layout: [0,8192) hdr  (line b: +0 f32 pos_sum, +4 u32 npos,
//   +256 f32 neg_result; gticket at ws+8188)
// [8192,..)   p_nhi/p_hsum/p_npos/p_psum/p_nwin : 5 x u32[3456]
// [77312,..)  wkey/widx/wloss : 3 x [3456][WBCAP]
#define OFF_PART 8192
#define PARTN (NBLK2 * BATCH)          // 3456
#define OFF_WIN (OFF_PART + 5 * PARTN * 4)

struct KeyPairs { unsigned k[2 * BATCH]; };

__host__ __device__ __forceinline__ void tf2x32(unsigned k0, unsigned k1,
                                                unsigned x0, unsigned x1,
                                                unsigned& o0, unsigned& o1)
{
  unsigned ks0 = k0, ks1 = k1, ks2 = k0 ^ k1 ^ 0x1BD11BDAu;
  x0 += ks0; x1 += ks1;
#define TF_R(r) { x0 += x1; x1 = __builtin_rotateleft32(x1, r); x1 ^= x0; }
  TF_R(13) TF_R(15) TF_R(26) TF_R(6)
  x0 += ks1; x1 += ks2 + 1u;
  TF_R(17) TF_R(29) TF_R(16) TF_R(24)
  x0 += ks2; x1 += ks0 + 2u;
  TF_R(13) TF_R(15) TF_R(26) TF_R(6)
  x0 += ks0; x1 += ks1 + 3u;
  TF_R(17) TF_R(29) TF_R(16) TF_R(24)
  x0 += ks1; x1 += ks2 + 4u;
  TF_R(13) TF_R(15) TF_R(26) TF_R(6)
  x0 += ks2; x1 += ks0 + 5u;
#undef TF_R
  o0 = x0; o1 = x1;
}

__device__ __forceinline__ float lossf(float x, float t, float m)
{
  float e  = __expf(-x);
  float p  = __fdividef(1.0f, 1.0f + e);
  p = fminf(fmaxf(p, 1e-4f), 1.0f - 1e-4f);
  bool is_pos = (t == 1.0f);
  float alpha = is_pos ? 0.75f : 0.25f;
  float pw = is_pos ? (1.0f - p) : p;
  float soft = __logf(1.0f + __expf(-fabsf(x)));
  float bce = fmaxf(x, 0.0f) - x * t + soft;
  float L = (m == 0.0f) ? alpha * pw * pw * bce : 0.0f;
  if (is_pos && p < 0.8f) L *= 4.0f;
  if (!is_pos && p > 0.5f)
    L *= 1.5f + fminf(fmaxf((p - 0.5f) * 5.0f, 0.0f), 1.0f) * 0.5f;
  return L;
}

__global__ __launch_bounds__(256, 2) void mono(
    const float* __restrict__ pred, const float* __restrict__ target,
    const float* __restrict__ mask, char* __restrict__ ws, KeyPairs kp)
{
  const int b = blockIdx.y;
  const int tid = threadIdx.x;
  const unsigned blk = blockIdx.x;
  const unsigned rb = (unsigned)b * NBLK2 + blk;
  const unsigned tbase = blk * 4096u;            // block's 4096-element chunk
  const unsigned q0 = tbase + (unsigned)tid * 4u; // group-0 quad (coalesced)
  const size_t sbase = (size_t)b * NPTS;
  const unsigned k0 = kp.k[2 * b], k1 = kp.k[2 * b + 1];

  unsigned* p_nhi  = (unsigned*)(ws + OFF_PART);
  unsigned* p_hsum = p_nhi + PARTN;
  unsigned* p_npos = p_hsum + PARTN;
  unsigned* p_psum = p_npos + PARTN;
  unsigned* p_nwin = p_psum + PARTN;
  unsigned* wkeyg  = (unsigned*)(ws + OFF_WIN);
  unsigned* widxg  = wkeyg + (size_t)PARTN * WBCAP;
  float*    wlossg = (float*)(widxg + (size_t)PARTN * WBCAP);

  if (b == 0 && blk == 0 && tid == 0)
    *(unsigned*)(ws + 8188) = 0u;   // zero gticket (visible at kernel boundary)

  __shared__ unsigned s_n, s_nhi, s_npos, s_wn, s_fail;
  __shared__ float    s_psum, s_hsum;
  __shared__ unsigned s_si[SCAP], s_skey[SCAP];

  if (tid == 0) { s_n = 0; s_nhi = 0; s_npos = 0; s_wn = 0; s_fail = 0;
                  s_psum = 0.0f; s_hsum = 0.0f; }
  __syncthreads();

  // coalesced loads: element for slot r (r = g*4+c) is q0 + g*1024 + c
  float4 t4a = *reinterpret_cast<const float4*>(target + sbase + q0);
  float4 t4b = *reinterpret_cast<const float4*>(target + sbase + q0 + 1024u);
  float4 t4c = *reinterpret_cast<const float4*>(target + sbase + q0 + 2048u);
  float4 t4d = *reinterpret_cast<const float4*>(target + sbase + q0 + 3072u);
  float tv[16] = { t4a.x, t4a.y, t4a.z, t4a.w, t4b.x, t4b.y, t4b.z, t4b.w,
                   t4c.x, t4c.y, t4c.z, t4c.w, t4d.x, t4d.y, t4d.z, t4d.w };

  unsigned kw[16];
#pragma unroll
  for (int r = 0; r < 16; ++r) {
    unsigned idx = q0 + (unsigned)(r >> 2) * 1024u + (unsigned)(r & 3);
    unsigned o0, o1;
    tf2x32(k0, k1, 0u, idx, o0, o1);              // partitionable: (0, i)
    kw[r] = o0 ^ o1;                               // raw word; key = kw>>9
  }

  unsigned posm = 0, him = 0, winm = 0;
#pragma unroll
  for (int r = 0; r < 16; ++r) {
    bool c  = (tv[r] == 0.0f) && (kw[r] >= THRESH_W);
    bool hi = c && (kw[r] >= HI_W);
    bool wn = c && !hi && (kw[r] >= TLO_W);
    him  |= (unsigned)hi << r;
    winm |= (unsigned)wn << r;
    posm |= (unsigned)(tv[r] == 1.0f) << r;
  }

  const unsigned flags = him | winm | posm;
  if (flags) {
    unsigned nf = (unsigned)__popc(flags);
    unsigned base = atomicAdd(&s_n, nf);
    unsigned j = 0;
#pragma unroll
    for (int r = 0; r < 16; ++r) {
      if ((flags >> r) & 1u) {
        unsigned idx = q0 + (unsigned)(r >> 2) * 1024u + (unsigned)(r & 3);
        unsigned cls = ((posm >> r) & 1u) ? 2u : (((winm >> r) & 1u) ? 1u : 0u);
        unsigned p = base + j; ++j;
        if (p < SCAP) {
          s_si[p] = idx | (cls << 20);
          s_skey[p] = kw[r] >> 9;
        } else {
          // inline overflow path (probability ~0): exact regardless
          float x = pred[sbase + idx], m = mask[sbase + idx];
          float L = lossf(x, (cls == 2u) ? 1.0f : 0.0f, m);
          if (cls == 2u) { atomicAdd(&s_psum, L); atomicAdd(&s_npos, 1u); }
          else if (cls == 0u) { atomicAdd(&s_hsum, L); atomicAdd(&s_nhi, 1u); }
          else {
            unsigned g = atomicAdd(&s_wn, 1u);
            if (g < WBCAP) {
              size_t o = (size_t)rb * WBCAP + g;
              wkeyg[o] = kw[r] >> 9; widxg[o] = idx; wlossg[o] = L;
            } else atomicOr(&s_fail, 1u);
          }
        }
      }
    }
  }
  __syncthreads();

  // compacted processing: n <= SCAP < 256 -> single step
  const unsigned n = s_n < SCAP ? s_n : SCAP;
  unsigned rec = (tid < (int)n) ? s_si[tid] : 0u;
  unsigned cls = (tid < (int)n) ? (rec >> 20) : 3u;
  unsigned i = rec & 0xFFFFFu;
  float L = 0.0f;
  if (cls < 3u) {
    float x = pred[sbase + i], m = mask[sbase + i];
    L = lossf(x, (cls == 2u) ? 1.0f : 0.0f, m);
  }
  if (cls == 2u) { atomicAdd(&s_psum, L); atomicAdd(&s_npos, 1u); }
  else if (cls == 0u) { atomicAdd(&s_hsum, L); atomicAdd(&s_nhi, 1u); }
  else if (cls == 1u) {
    unsigned g = atomicAdd(&s_wn, 1u);
    if (g < WBCAP) {
      size_t o = (size_t)rb * WBCAP + g;
      wkeyg[o] = s_skey[tid]; widxg[o] = i; wlossg[o] = L;
    } else atomicOr(&s_fail, 1u);
  }
  __syncthreads();

  if (tid == 0) {   // every field written every launch -> no zeroing needed
    p_nhi[rb]  = s_nhi;
    p_hsum[rb] = __float_as_uint(s_hsum);
    p_npos[rb] = s_npos;
    p_psum[rb] = __float_as_uint(s_psum);
    unsigned wn = s_wn;
    unsigned fail = (s_fail || wn > WBCAP) ? 0x80000000u : 0u;
    p_nwin[rb] = (wn < WBCAP ? wn : WBCAP) | fail;
  }
}

// select_k: 16 blocks. Reduce partials + scan + gather window into LDS, then
// exact selection (tie: lowest idx). Full-rescan exact fallback (dead).
// Last block (gticket) computes the final 2-float output.
__global__ __launch_bounds__(256) void select_k(
    const float* __restrict__ pred, const float* __restrict__ target,
    const float* __restrict__ mask, char* __restrict__ ws,
    float* __restrict__ out, KeyPairs kp)
{
  const int b = blockIdx.x;
  const int tid = threadIdx.x;
  char* line = ws + (size_t)b * HDRB;
  unsigned* gticket = (unsigned*)(ws + 8188);

  const unsigned* p_nhi  = (const unsigned*)(ws + OFF_PART);
  const unsigned* p_hsum = p_nhi + PARTN;
  const unsigned* p_npos = p_hsum + PARTN;
  const unsigned* p_psum = p_npos + PARTN;
  const unsigned* p_nwin = p_psum + PARTN;
  const unsigned* wkeyg  = (const unsigned*)(ws + OFF_WIN);
  const unsigned* widxg  = wkeyg + (size_t)PARTN * WBCAP;
  const float*    wlossg = (const float*)(widxg + (size_t)PARTN * WBCAP);

  __shared__ unsigned skey[WCAP], sidx[WCAP];
  __shared__ float    sls[WCAP];
  __shared__ unsigned sc[256];
  __shared__ unsigned redu[256];
  __shared__ float    redf[256];
  __shared__ unsigned s_eqc, s_u1, s_tick;
  __shared__ unsigned s_eqi[BCAP];
  __shared__ float    s_eql[BCAP];
  __shared__ float    s_f;

  auto redSumU = [&](unsigned v) -> unsigned {
    redu[tid] = v; __syncthreads();
    for (int s = 128; s > 0; s >>= 1) { if (tid < s) redu[tid] += redu[tid + s]; __syncthreads(); }
    unsigned r = redu[0]; __syncthreads(); return r;
  };
  auto redSumF = [&](float v) -> float {
    redf[tid] = v; __syncthreads();
    for (int s = 128; s > 0; s >>= 1) { if (tid < s) redf[tid] += redf[tid + s]; __syncthreads(); }
    float r = redf[0]; __syncthreads(); return r;
  };

  // ---- reduce per-block partials (216 regions) ----
  unsigned mynhi = 0, mynpos = 0, mycnt = 0, myfail = 0;
  float myh = 0.0f, myp = 0.0f;
  unsigned myrb = (unsigned)b * NBLK2 + (unsigned)tid;
  if (tid < (int)NBLK2) {
    mynhi = p_nhi[myrb];
    myh   = __uint_as_float(p_hsum[myrb]);
    mynpos = p_npos[myrb];
    myp   = __uint_as_float(p_psum[myrb]);
    unsigned w = p_nwin[myrb];
    mycnt = w & 0x7FFFFFFFu;
    myfail = w >> 31;
  }
  const unsigned n_hi = redSumU(mynhi);
  const float sum_hi = redSumF(myh);
  const unsigned npos = redSumU(mynpos);
  const float pos_sum = redSumF(myp);
  const unsigned failN = redSumU(myfail);

  // exclusive scan of window counts (Hillis-Steele over 256)
  sc[tid] = mycnt; __syncthreads();
  for (int s = 1; s < 256; s <<= 1) {
    unsigned v = (tid >= s) ? sc[tid - s] : 0u;
    __syncthreads();
    sc[tid] += v;
    __syncthreads();
  }
  const unsigned nw = sc[255];
  const unsigned wbase = sc[tid] - mycnt;

  const unsigned k = (npos > 0u) ? ((100u * npos < KSEL) ? 100u * npos : KSEL) : 100u;
  const bool bad = failN || (n_hi > KSEL) || (n_hi + nw < KSEL) ||
                   (nw > WCAP) || (k < KSEL);

  float res = 0.0f;

  if (!bad) {
    // gather window entries into LDS (contiguous)
    if (tid < (int)NBLK2) {
      size_t src = (size_t)myrb * WBCAP;
      for (unsigned e = 0; e < mycnt; ++e) {
        skey[wbase + e] = wkeyg[src + e];
        sidx[wbase + e] = widxg[src + e];
        sls[wbase + e]  = wlossg[src + e];
      }
    }
    __syncthreads();
    const unsigned need = KSEL - n_hi;
    if (need == 0) res = sum_hi;
    else {
      auto cGe = [&](unsigned v) -> unsigned {
        unsigned c = 0;
        for (unsigned e = tid; e < nw; e += 256) c += (skey[e] >= v) ? 1u : 0u;
        return redSumU(c);
      };
      unsigned lo = TLO, hi = THI;                 // cGe(TLO)=nw>=need
      while (lo < hi) {
        unsigned mid = lo + (hi - lo + 1u) / 2u;
        if (cGe(mid) >= need) lo = mid; else hi = mid - 1u;
      }
      const unsigned V = lo;
      const unsigned c_gt = cGe(V + 1u);
      const unsigned m = need - c_gt;
      float s = 0.0f;
      for (unsigned e = tid; e < nw; e += 256) if (skey[e] > V) s += sls[e];
      float sum_gt = redSumF(s);
      if (tid == 0) s_eqc = 0;
      __syncthreads();
      for (unsigned e = tid; e < nw; e += 256) {
        if (skey[e] == V) {
          unsigned p = atomicAdd(&s_eqc, 1u);
          if (p < BCAP) { s_eqi[p] = sidx[e]; s_eql[p] = sls[e]; }
        }
      }
      __syncthreads();
      if (tid == 0) {
        unsigned ne = s_eqc; if (ne > BCAP) ne = BCAP;
        unsigned mm = (m < ne) ? m : ne;
        float es = 0.0f;
        for (unsigned a = 0; a < mm; ++a) {        // idx asc (LDS only)
          unsigned best = a;
          for (unsigned q = a + 1; q < ne; ++q)
            if (s_eqi[q] < s_eqi[best]) best = q;
          unsigned ti = s_eqi[a]; s_eqi[a] = s_eqi[best]; s_eqi[best] = ti;
          float tl = s_eql[a]; s_eql[a] = s_eql[best]; s_eql[best] = tl;
          es += s_eql[a];
        }
        s_f = sum_hi + sum_gt + es;
      }
      __syncthreads();
      res = s_f;
    }
  } else {
    // ---- exact fallback via full rescans (dead for this data) ----
    const float* T = target + (size_t)b * NPTS;
    const float* P = pred   + (size_t)b * NPTS;
    const float* M = mask   + (size_t)b * NPTS;
    const unsigned k0 = kp.k[2 * b], k1 = kp.k[2 * b + 1];
    auto keyOf = [&](unsigned i) -> unsigned {
      unsigned o0, o1; tf2x32(k0, k1, 0u, i, o0, o1); return (o0 ^ o1) >> 9;
    };
    auto cKeyGe = [&](unsigned v) -> unsigned {
      unsigned c = 0;
      for (unsigned i = tid; i < NPTS; i += 256)
        if (T[i] == 0.0f && keyOf(i) >= v) c++;
      return redSumU(c);
    };
    const unsigned cnt = cKeyGe(THRESH_KEY);       // exact candidate count
    const bool take_all = (cnt <= KSEL);
    const unsigned nsel = take_all ? cnt : KSEL;
    unsigned V = 0, idxcut = 0xffffffffu; float eq_sum = 0.0f;
    if (!take_all) {
      unsigned lo = THRESH_KEY, hi = KEYMAX;
      while (lo < hi) {
        unsigned mid = lo + (hi - lo + 1u) / 2u;
        if (cKeyGe(mid) >= KSEL) lo = mid; else hi = mid - 1u;
      }
      V = lo;
      unsigned c_gt = cKeyGe(V + 1u);
      unsigned needq = KSEL - c_gt;
      if (tid == 0) s_eqc = 0;
      __syncthreads();
      for (unsigned i = tid; i < NPTS; i += 256)
        if (T[i] == 0.0f && keyOf(i) == V) {
          unsigned p = atomicAdd(&s_eqc, 1u);
          if (p < BCAP) s_eqi[p] = i;
        }
      __syncthreads();
      if (tid == 0) {
        unsigned ne = s_eqc; if (ne > BCAP) ne = BCAP;
        unsigned mm = (needq < ne) ? needq : ne;
        float es = 0.0f; unsigned ic = 0xffffffffu;
        for (unsigned a = 0; a < mm; ++a) {
          unsigned best = a;
          for (unsigned q = a + 1; q < ne; ++q)
            if (s_eqi[q] < s_eqi[best]) best = q;
          unsigned ti = s_eqi[a]; s_eqi[a] = s_eqi[best]; s_eqi[best] = ti;
          es += lossf(P[s_eqi[a]], 0.0f, M[s_eqi[a]]);
        }
        if (mm > 0) ic = s_eqi[mm - 1];
        s_f = es; s_u1 = ic;
      }
      __syncthreads();
      eq_sum = s_f; idxcut = s_u1;
      __syncthreads();
    }
    if (k >= nsel) {
      float s = 0.0f;
      for (unsigned i = tid; i < NPTS; i += 256) {
        if (T[i] != 0.0f) continue;
        unsigned kk = keyOf(i);
        if (kk < THRESH_KEY) continue;
        if (take_all || kk > V) s += lossf(P[i], 0.0f, M[i]);
      }
      res = redSumF(s) + (take_all ? 0.0f : eq_sum);
    } else {
      auto cLossGe = [&](unsigned w) -> unsigned {
        unsigned c = 0;
        for (unsigned i = tid; i < NPTS; i += 256) {
          if (T[i] != 0.0f) continue;
          unsigned kk = keyOf(i);
          if (kk < THRESH_KEY) continue;
          bool sel = take_all || kk > V || (kk == V && i <= idxcut);
          if (sel && __float_as_uint(lossf(P[i], 0.0f, M[i])) >= w) c++;
        }
        return redSumU(c);
      };
      unsigned lo = 0u, hi = 0x7f7fffffu;
      while (lo < hi) {
        unsigned mid = lo + (hi - lo + 1u) / 2u;
        if (cLossGe(mid) >= k) lo = mid; else hi = mid - 1u;
      }
      unsigned cgt = cLossGe(lo + 1u);
      float s = 0.0f;
      for (unsigned i = tid; i < NPTS; i += 256) {
        if (T[i] != 0.0f) continue;
        unsigned kk = keyOf(i);
        if (kk < THRESH_KEY) continue;
        bool sel = take_all || kk > V || (kk == V && i <= idxcut);
        float L = lossf(P[i], 0.0f, M[i]);
        if (sel && __float_as_uint(L) > lo) s += L;
      }
      res = redSumF(s) + (float)(k - cgt) * __uint_as_float(lo);
    }
  }

  // publish per-sample stats + result (full overwrite), ticket, finalize
  if (tid == 0) {
    atomicExch((float*)(line + 0), pos_sum);
    atomicExch((unsigned*)(line + 4), npos);
    atomicExch((float*)(line + 256), res);
    __threadfence();
    s_tick = atomicAdd(gticket, 1u);
  }
  __syncthreads();
  if (s_tick == BATCH - 1) {
    float ps = 0.0f, ns = 0.0f;
    if (tid < BATCH) {
      char* ln = ws + (size_t)tid * HDRB;
      float pp = atomicAdd((float*)(ln + 0), 0.0f);
      unsigned np = atomicAdd((unsigned*)(ln + 4), 0u);
      float nr = atomicAdd((float*)(ln + 256), 0.0f);
      float denom = (np > 0u) ? fmaxf((float)np, 1.0f) : 1.0f;
      ps = pp / denom;
      ns = nr / denom;
    }
#pragma unroll
    for (int s = 8; s > 0; s >>= 1) {
      ps += __shfl_down(ps, s, 64);
      ns += __shfl_down(ns, s, 64);
    }
    if (tid == 0) {
      out[0] = ps / (float)BATCH;
      out[1] = ns / (float)BATCH;
    }
  }
}

extern "C" void kernel_launch(void* const* d_in, const int* in_sizes, int n_in,
                              void* d_out, int out_size, void* d_ws, size_t ws_size,
                              hipStream_t stream)
{
  const float* pred   = (const float*)d_in[0];
  const float* target = (const float*)d_in[1];
  const float* mask   = (const float*)d_in[2];
  float* out = (float*)d_out;

  const size_t FIXED = OFF_WIN + 3 * (size_t)PARTN * WBCAP * 4;   // ~1.74 MB
  if (ws_size < FIXED || out_size < 2) {
    hipMemsetAsync(d_out, 0, sizeof(float) * (out_size > 0 ? out_size : 1), stream);
    return;
  }

  char* ws = (char*)d_ws;

  KeyPairs kp;
  for (unsigned b = 0; b < BATCH; ++b) {
    unsigned o0, o1;
    tf2x32(0u, 42u, 0u, b, o0, o1);
    kp.k[2 * b] = o0; kp.k[2 * b + 1] = o1;
  }

  mono<<<dim3(NBLK2, BATCH), 256, 0, stream>>>(pred, target, mask, ws, kp);
  select_k<<<BATCH, 256, 0, stream>>>(pred, target, mask, ws, out, kp);
}